// Round 6
// baseline (96.908 us; speedup 1.0000x reference)
//
#include <hip/hip_runtime.h>
#include <hip/hip_bf16.h>
#include <math.h>

// GAT: B=4, N=2048, in=128, out=32, heads=4
// outputs: H_new [4,2048,128] f32 (1048576) then alpha [4,4,2048,2048] f32 (67108864)

typedef float f32x4 __attribute__((ext_vector_type(4)));
typedef short bf16x8 __attribute__((ext_vector_type(8)));

#define LRELU 0.2f
#define LOG2E 1.44269504088896f
#define EXP2(x) __builtin_amdgcn_exp2f(x)

__device__ inline ushort f2b(float x) {
    unsigned int u = __float_as_uint(x);
    u += 0x7fffu + ((u >> 16) & 1u);   // RNE
    return (ushort)(u >> 16);
}

// ---------------- k0: pack (adj + I) into bitmask, 32 u64 per row -------------------------
__global__ __launch_bounds__(256) void k0_mask(const float* __restrict__ adj,
                                               unsigned long long* __restrict__ maskG) {
    int t = threadIdx.x;
    int lane = t & 63, w = t >> 6;
    int row = blockIdx.x * 4 + w;   // 512 blocks x 4 rows
    const float* arow = adj + (size_t)row * 2048;
    #pragma unroll
    for (int i = 0; i < 32; ++i) {
        float v = arow[i * 64 + lane];
        unsigned long long bm = __ballot((v != 0.f) || (i * 64 + lane == row));
        if (lane == 0) maskG[row * 32 + i] = bm;
    }
}

// ---------------- k1: Ht = H @ W[h], src/dst dots, write Ht^T as bf16 [bh][f][k] -----------
__global__ __launch_bounds__(256) void k1_ht(const float* __restrict__ H,
                                             const float* __restrict__ W,
                                             const float* __restrict__ a,
                                             __hip_bfloat16* __restrict__ HtT,
                                             float* __restrict__ src,
                                             float* __restrict__ dst) {
    __shared__ float Ws[128 * 32];      // 16 KB
    __shared__ float Hs[8 * 128];       // 4 KB
    __shared__ float T[32 * 9];         // transpose buffer, padded

    int t = threadIdx.x;
    int g0 = blockIdx.x * 8;            // first global row id in [0, 32768)
    int bh = g0 >> 11;
    int n0 = g0 & 2047;
    int b = bh >> 2, h = bh & 3;

    #pragma unroll
    for (int u = 0; u < 16; ++u) Ws[u * 256 + t] = W[h * 4096 + u * 256 + t];
    #pragma unroll
    for (int u = 0; u < 4; ++u) {
        int s = u * 256 + t;
        int r = s >> 7, i = s & 127;
        Hs[s] = H[(size_t)(b * 2048 + n0 + r) * 128 + i];
    }
    __syncthreads();

    int r = t >> 5, f = t & 31;
    float acc = 0.f;
    #pragma unroll
    for (int i = 0; i < 128; ++i) acc += Hs[r * 128 + i] * Ws[i * 32 + f];

    float sv = acc * a[h * 64 + f];
    float dv = acc * a[h * 64 + 32 + f];
    #pragma unroll
    for (int off = 16; off; off >>= 1) {
        sv += __shfl_xor(sv, off);
        dv += __shfl_xor(dv, off);
    }
    if (f == 0) { src[g0 + r] = sv; dst[g0 + r] = dv; }

    T[f * 9 + r] = acc;
    __syncthreads();
    if (t < 128) {
        int fp = t >> 2, p = t & 3;
        __hip_bfloat162 v2;
        v2.x = __float2bfloat16(T[fp * 9 + 2 * p]);
        v2.y = __float2bfloat16(T[fp * 9 + 2 * p + 1]);
        *(__hip_bfloat162*)&HtT[(size_t)(bh * 32 + fp) * 2048 + n0 + 2 * p] = v2;
    }
}

// ---------------- fused: bitmask softmax -> alpha (nt-store) -> MFMA -> ELU -> H_new -------
// grid (64 mtiles of 32 rows, 16 bh), block 256 (4 waves).
__global__ __launch_bounds__(256) void k2_fused(const unsigned long long* __restrict__ maskG,
                                                const float* __restrict__ src,
                                                const float* __restrict__ dst,
                                                const __hip_bfloat16* __restrict__ HtT,
                                                float* __restrict__ alpha,
                                                float* __restrict__ outH) {
    __shared__ float dstS[2048];                        // 8 KB (pre-scaled by LOG2E)
    __shared__ unsigned long long maskS[32 * 32];       // 8 KB (this block's 32 mask rows)
    __shared__ float rowInvS[32], rowSrcS[32];
    __shared__ __align__(16) ushort As[2][32 * 128];    // 16 KB dbuf, XOR-swizzled
    __shared__ __align__(16) ushort Bs[2][32 * 128];    // 16 KB dbuf, XOR-swizzled

    int t = threadIdx.x;
    int mtile = blockIdx.x;   // 64
    int bh    = blockIdx.y;   // 16
    int lane = t & 63, w = t >> 6;
    int b = bh >> 2, h = bh & 3;
    int row0 = mtile * 32;

    const float4* dst4g = (const float4*)(dst + bh * 2048);
    #pragma unroll
    for (int u = 0; u < 2; ++u) {
        float4 v = dst4g[u * 256 + t];
        v.x *= LOG2E; v.y *= LOG2E; v.z *= LOG2E; v.w *= LOG2E;
        *(float4*)&dstS[(u * 256 + t) * 4] = v;
    }
    #pragma unroll
    for (int u = 0; u < 4; ++u) maskS[u * 256 + t] = maskG[row0 * 32 + u * 256 + t];
    if (t < 32) rowSrcS[t] = src[bh * 2048 + row0 + t] * LOG2E;
    __syncthreads();

    // ---- pass A: per-row sum of exp2 (no max: |e| bounded, masked -> 0) ----
    for (int rr = 0; rr < 8; ++rr) {
        int r = w * 8 + rr;
        float sn = rowSrcS[r];
        float S = 0.f;
        #pragma unroll
        for (int u = 0; u < 8; ++u) {
            unsigned long long m64 = maskS[r * 32 + 4 * u + (lane >> 4)];
            unsigned bits4 = (unsigned)(m64 >> (4 * (lane & 15))) & 0xFu;
            int jb = (u * 64 + lane) * 4;
            float4 dv = *(const float4*)&dstS[jb];
            float dj[4] = {dv.x, dv.y, dv.z, dv.w};
            #pragma unroll
            for (int q = 0; q < 4; ++q) {
                float ee = sn + dj[q];
                ee = fmaxf(ee, LRELU * ee);
                S += (bits4 & (1u << q)) ? EXP2(ee) : 0.f;
            }
        }
        #pragma unroll
        for (int off = 32; off; off >>= 1) S += __shfl_xor(S, off);
        if (lane == 0) rowInvS[r] = 1.f / S;
    }
    __syncthreads();

    // ---- pass B: dbuf pipeline, one lgkm-only barrier per 128-wide K-chunk ----
    f32x4 acc = {0.f, 0.f, 0.f, 0.f};
    int wr = w >> 1, wc = w & 1;
    int l15 = lane & 15, l4 = lane >> 4;
    const ushort* Bbase = (const ushort*)HtT + (size_t)bh * 32 * 2048;
    float* alphaRow = alpha + (size_t)(bh * 2048 + row0) * 2048;

    int sr = t >> 5;            // rows sr, sr+8, sr+16, sr+24
    int sc4 = t & 31;
    int bnr = t >> 4;           // B rows bnr, bnr+16
    int bc8 = t & 15;

    auto stage_compute = [&](int k0, const uint4* bvr, ushort* Asb, ushort* Bsb) {
        int jb = k0 + sc4 * 4;
        float4 dv = *(const float4*)&dstS[jb];
        float dj[4] = {dv.x, dv.y, dv.z, dv.w};
        int kwo = (k0 >> 6) + (sc4 >> 4);
        int bsh = 4 * (sc4 & 15);
        #pragma unroll
        for (int u = 0; u < 4; ++u) {
            int r = sr + u * 8;
            unsigned bits4 = (unsigned)(maskS[r * 32 + kwo] >> bsh) & 0xFu;
            float sn = rowSrcS[r], invS = rowInvS[r];
            float o[4];
            #pragma unroll
            for (int q = 0; q < 4; ++q) {
                float ee = sn + dj[q];
                ee = fmaxf(ee, LRELU * ee);
                float p = EXP2(ee) * invS;
                o[q] = (bits4 & (1u << q)) ? p : 0.f;
            }
            f32x4 ov = {o[0], o[1], o[2], o[3]};
            __builtin_nontemporal_store(ov, (f32x4*)(alphaRow + (size_t)r * 2048 + jb));
            ushort4 bv;
            bv.x = f2b(o[0]); bv.y = f2b(o[1]); bv.z = f2b(o[2]); bv.w = f2b(o[3]);
            *(ushort4*)&Asb[(r * 128 + sc4 * 4) ^ ((r & 7) << 3)] = bv;
        }
        #pragma unroll
        for (int u = 0; u < 2; ++u) {
            int nr = bnr + u * 16;
            *(uint4*)&Bsb[(nr * 128 + bc8 * 8) ^ ((nr & 7) << 3)] = bvr[u];
        }
    };

    // prologue: load + stage chunk 0
    {
        uint4 bvr[2];
        #pragma unroll
        for (int u = 0; u < 2; ++u)
            bvr[u] = *(const uint4*)(Bbase + (size_t)(bnr + u * 16) * 2048 + bc8 * 8);
        stage_compute(0, bvr, As[0], Bs[0]);
    }

    for (int kc = 0; kc < 16; ++kc) {
        asm volatile("s_waitcnt lgkmcnt(0)" ::: "memory");
        __builtin_amdgcn_s_barrier();

        uint4 bvr[2];
        int kn = (kc + 1) * 128;
        if (kc < 15) {
            #pragma unroll
            for (int u = 0; u < 2; ++u)
                bvr[u] = *(const uint4*)(Bbase + (size_t)(bnr + u * 16) * 2048 + kn + bc8 * 8);
        }

        const ushort* Asb = As[kc & 1];
        const ushort* Bsb = Bs[kc & 1];
        int arow = wr * 16 + l15;
        int bcol = wc * 16 + l15;
        #pragma unroll
        for (int kk = 0; kk < 4; ++kk) {
            int colk = kk * 32 + l4 * 8;
            bf16x8 avf = *(const bf16x8*)&Asb[(arow * 128 + colk) ^ ((arow & 7) << 3)];
            bf16x8 bvf = *(const bf16x8*)&Bsb[(bcol * 128 + colk) ^ ((bcol & 7) << 3)];
            acc = __builtin_amdgcn_mfma_f32_16x16x32_bf16(avf, bvf, acc, 0, 0, 0);
        }

        if (kc < 15) stage_compute(kn, bvr, As[(kc + 1) & 1], Bs[(kc + 1) & 1]);
    }

    // epilogue: ELU + write H_new[b][node][h*32 + col]
    #pragma unroll
    for (int q = 0; q < 4; ++q) {
        int node = row0 + wr * 16 + l4 * 4 + q;
        float v = acc[q];
        v = (v > 0.f) ? v : expm1f(v);
        outH[(size_t)(b * 2048 + node) * 128 + h * 32 + wc * 16 + l15] = v;
    }
}

extern "C" void kernel_launch(void* const* d_in, const int* in_sizes, int n_in,
                              void* d_out, int out_size, void* d_ws, size_t ws_size,
                              hipStream_t stream) {
    const float* H   = (const float*)d_in[0];
    const float* adj = (const float*)d_in[1];
    const float* W   = (const float*)d_in[2];
    const float* a   = (const float*)d_in[3];

    float* outH  = (float*)d_out;
    float* alpha = outH + (size_t)4 * 2048 * 128;   // 1048576

    char* ws = (char*)d_ws;
    __hip_bfloat16* HtT = (__hip_bfloat16*)ws;                   // 2 MB
    float* src = (float*)(ws + 2 * 1024 * 1024);                 // 128 KB
    float* dst = src + 32768;                                    // 128 KB
    unsigned long long* maskG =
        (unsigned long long*)(ws + 2 * 1024 * 1024 + 256 * 1024); // 512 KB

    k0_mask<<<512, 256, 0, stream>>>(adj, maskG);
    k1_ht<<<4096, 256, 0, stream>>>(H, W, a, HtT, src, dst);
    k2_fused<<<dim3(64, 16), 256, 0, stream>>>(maskG, src, dst, HtT, alpha, outH);
}

// Round 7
// 88.490 us; speedup vs baseline: 1.0951x; 1.0951x over previous
//
#include <hip/hip_runtime.h>
#include <hip/hip_bf16.h>
#include <math.h>

// GAT: B=4, N=2048, in=128, out=32, heads=4
// outputs: H_new [4,2048,128] f32 (1048576) then alpha [4,4,2048,2048] f32 (67108864)

typedef float f32x4 __attribute__((ext_vector_type(4)));
typedef short bf16x8 __attribute__((ext_vector_type(8)));
typedef unsigned int u32;

#define LRELU 0.2f
#define LOG2E 1.44269504088896f
#define EXP2(x) __builtin_amdgcn_exp2f(x)

// ---------------- k0: adjI[row][col] = (adj!=0 || col==row) ? 1 : 0 (u8) ------------------
__global__ __launch_bounds__(256) void k0_adjI(const float* __restrict__ adj,
                                               unsigned char* __restrict__ adjI) {
    int idx = blockIdx.x * 256 + threadIdx.x;
    int e0 = idx * 4;
    int row = e0 >> 11;
    int c0 = e0 & 2047;
    float4 v = *(const float4*)(adj + (size_t)e0);
    uchar4 o;
    o.x = (v.x != 0.f || c0     == row) ? 1 : 0;
    o.y = (v.y != 0.f || c0 + 1 == row) ? 1 : 0;
    o.z = (v.z != 0.f || c0 + 2 == row) ? 1 : 0;
    o.w = (v.w != 0.f || c0 + 3 == row) ? 1 : 0;
    *(uchar4*)(adjI + (size_t)e0) = o;
}

// ---------------- k1: Ht = H @ W[h], src/dst dots, write Ht^T as bf16 [bh][f][k] -----------
__global__ __launch_bounds__(256) void k1_ht(const float* __restrict__ H,
                                             const float* __restrict__ W,
                                             const float* __restrict__ a,
                                             __hip_bfloat16* __restrict__ HtT,
                                             float* __restrict__ src,
                                             float* __restrict__ dst) {
    __shared__ float Ws[128 * 32];      // 16 KB
    __shared__ float Hs[8 * 128];       // 4 KB
    __shared__ float T[32 * 9];         // transpose buffer, padded

    int t = threadIdx.x;
    int g0 = blockIdx.x * 8;            // first global row id in [0, 32768)
    int bh = g0 >> 11;
    int n0 = g0 & 2047;
    int b = bh >> 2, h = bh & 3;

    #pragma unroll
    for (int u = 0; u < 16; ++u) Ws[u * 256 + t] = W[h * 4096 + u * 256 + t];
    #pragma unroll
    for (int u = 0; u < 4; ++u) {
        int s = u * 256 + t;
        int r = s >> 7, i = s & 127;
        Hs[s] = H[(size_t)(b * 2048 + n0 + r) * 128 + i];
    }
    __syncthreads();

    int r = t >> 5, f = t & 31;
    float acc = 0.f;
    #pragma unroll
    for (int i = 0; i < 128; ++i) acc += Hs[r * 128 + i] * Ws[i * 32 + f];

    float sv = acc * a[h * 64 + f];
    float dv = acc * a[h * 64 + 32 + f];
    #pragma unroll
    for (int off = 16; off; off >>= 1) {
        sv += __shfl_xor(sv, off);
        dv += __shfl_xor(dv, off);
    }
    if (f == 0) { src[g0 + r] = sv; dst[g0 + r] = dv; }

    T[f * 9 + r] = acc;
    __syncthreads();
    if (t < 128) {
        int fp = t >> 2, p = t & 3;
        __hip_bfloat162 v2;
        v2.x = __float2bfloat16(T[fp * 9 + 2 * p]);
        v2.y = __float2bfloat16(T[fp * 9 + 2 * p + 1]);
        *(__hip_bfloat162*)&HtT[(size_t)(bh * 32 + fp) * 2048 + n0 + 2 * p] = v2;
    }
}

// ---------------- fused: softmax -> alpha (nt-store) -> MFMA -> ELU -> H_new ---------------
// grid (64 mtiles of 32 rows, 16 bh), block 256 (4 waves). LDS ~24.7 KB -> 4 blocks/CU.
// In-loop barriers are lgkmcnt-only; vmcnt is never drained (stores/loads stay in flight).
__global__ __launch_bounds__(256, 4) void k2_fused(const unsigned char* __restrict__ adjI,
                                                   const float* __restrict__ src,
                                                   const float* __restrict__ dst,
                                                   const __hip_bfloat16* __restrict__ HtT,
                                                   float* __restrict__ alpha,
                                                   float* __restrict__ outH) {
    __shared__ float dstS[2048];                      // 8 KB (pre-scaled by LOG2E)
    __shared__ float rowL[32], rowSrcS[32];
    __shared__ __align__(16) ushort As[32 * 128];     // 8 KB, XOR-swizzled alpha tile (bf16)
    __shared__ __align__(16) ushort Bs[32 * 128];     // 8 KB, XOR-swizzled HtT tile

    int t = threadIdx.x;
    int mtile = blockIdx.x;   // 64
    int bh    = blockIdx.y;   // 16
    int lane = t & 63, w = t >> 6;
    int b = bh >> 2, h = bh & 3;
    int row0 = mtile * 32;

    const float4* dst4g = (const float4*)(dst + bh * 2048);
    #pragma unroll
    for (int u = 0; u < 2; ++u) {
        float4 v = dst4g[u * 256 + t];
        v.x *= LOG2E; v.y *= LOG2E; v.z *= LOG2E; v.w *= LOG2E;
        *(float4*)&dstS[(u * 256 + t) * 4] = v;
    }
    if (t < 32) rowSrcS[t] = src[bh * 2048 + row0 + t] * LOG2E;
    __syncthreads();

    // ---- pass A: per-row S = sum_j adjI * exp2(leaky(ee)); store L = -log2(S) ----
    for (int rr = 0; rr < 8; ++rr) {
        int r = w * 8 + rr;
        int gr = row0 + r;
        float sn = rowSrcS[r];
        const uint2* a8 = (const uint2*)(adjI + (size_t)gr * 2048);
        float S = 0.f;
        #pragma unroll
        for (int u = 0; u < 4; ++u) {
            uint2 ab = a8[u * 64 + lane];
            int jb = (u * 64 + lane) * 8;
            float4 dv0 = *(const float4*)&dstS[jb];
            float4 dv1 = *(const float4*)&dstS[jb + 4];
            float dj[8] = {dv0.x, dv0.y, dv0.z, dv0.w, dv1.x, dv1.y, dv1.z, dv1.w};
            #pragma unroll
            for (int q = 0; q < 8; ++q) {
                u32 word = (q < 4) ? ab.x : ab.y;
                float ajf = (float)((word >> (8 * (q & 3))) & 0xffu);
                float ee = sn + dj[q];
                float vm = fmaxf(ee, LRELU * ee);
                S = fmaf(EXP2(vm), ajf, S);
            }
        }
        #pragma unroll
        for (int off = 32; off; off >>= 1) S += __shfl_xor(S, off);
        if (lane == 0) rowL[r] = -__log2f(S);
    }
    __syncthreads();

    // ---- pass B: single-buffer pipeline, two lgkm-only barriers per 128-wide K-chunk ----
    f32x4 acc = {0.f, 0.f, 0.f, 0.f};
    int wr = w >> 1, wc = w & 1;
    int l15 = lane & 15, l4 = lane >> 4;
    const ushort* Bbase = (const ushort*)HtT + (size_t)bh * 32 * 2048;
    float* alphaRow = alpha + (size_t)(bh * 2048 + row0) * 2048;

    int sr = t >> 5;            // rows sr, sr+8, sr+16, sr+24
    int sc4 = t & 31;
    int bnr = t >> 4;           // B rows bnr, bnr+16
    int bc8 = t & 15;

    // per-thread row constants (rows sr + u*8)
    float snR[4], LR[4];
    #pragma unroll
    for (int u = 0; u < 4; ++u) { snR[u] = rowSrcS[sr + u * 8]; LR[u] = rowL[sr + u * 8]; }

    // prefetch chunk 0 into regs
    u32 a32[4]; uint4 bvr[2];
    #pragma unroll
    for (int u = 0; u < 4; ++u)
        a32[u] = *(const u32*)(adjI + (size_t)(row0 + sr + u * 8) * 2048 + sc4 * 4);
    #pragma unroll
    for (int u = 0; u < 2; ++u)
        bvr[u] = *(const uint4*)(Bbase + (size_t)(bnr + u * 16) * 2048 + bc8 * 8);

    for (int kc = 0; kc < 16; ++kc) {
        if (kc) {  // all waves finished ds_reads of previous chunk (operand waits imply drain)
            asm volatile("s_waitcnt lgkmcnt(0)" ::: "memory");
            __builtin_amdgcn_s_barrier();
        }
        int jb = kc * 128 + sc4 * 4;
        float4 dv = *(const float4*)&dstS[jb];
        float dj[4] = {dv.x, dv.y, dv.z, dv.w};
        #pragma unroll
        for (int u = 0; u < 4; ++u) {
            int r = sr + u * 8;
            float sn = snR[u], L = LR[u];
            u32 ab = a32[u];
            float o[4];
            #pragma unroll
            for (int q = 0; q < 4; ++q) {
                float ajf = (float)((ab >> (8 * q)) & 0xffu);
                float ee = sn + dj[q];
                float v1 = ee + L;
                float v2 = fmaf(ee, LRELU, L);
                float vm = fmaxf(v1, v2);
                o[q] = EXP2(vm) * ajf;
            }
            f32x4 ov = {o[0], o[1], o[2], o[3]};
            __builtin_nontemporal_store(ov, (f32x4*)(alphaRow + (size_t)r * 2048 + jb));
            u32 lo, hi;
            asm volatile("v_cvt_pk_bf16_f32 %0, %1, %2" : "=v"(lo) : "v"(o[0]), "v"(o[1]));
            asm volatile("v_cvt_pk_bf16_f32 %0, %1, %2" : "=v"(hi) : "v"(o[2]), "v"(o[3]));
            uint2 pk = {lo, hi};
            *(uint2*)&As[(r * 128 + sc4 * 4) ^ ((r & 7) << 3)] = pk;
        }
        #pragma unroll
        for (int u = 0; u < 2; ++u) {
            int nr = bnr + u * 16;
            *(uint4*)&Bs[(nr * 128 + bc8 * 8) ^ ((nr & 7) << 3)] = bvr[u];
        }

        // prefetch next chunk into regs (hidden under barrier + MFMA)
        if (kc < 15) {
            int jn = (kc + 1) * 128 + sc4 * 4;
            #pragma unroll
            for (int u = 0; u < 4; ++u)
                a32[u] = *(const u32*)(adjI + (size_t)(row0 + sr + u * 8) * 2048 + jn);
            #pragma unroll
            for (int u = 0; u < 2; ++u)
                bvr[u] = *(const uint4*)(Bbase + (size_t)(bnr + u * 16) * 2048 + (kc + 1) * 128 + bc8 * 8);
        }

        asm volatile("s_waitcnt lgkmcnt(0)" ::: "memory");
        __builtin_amdgcn_s_barrier();

        int arow = wr * 16 + l15;
        int bcol = wc * 16 + l15;
        #pragma unroll
        for (int kk = 0; kk < 4; ++kk) {
            int colk = kk * 32 + l4 * 8;
            bf16x8 avf = *(const bf16x8*)&As[(arow * 128 + colk) ^ ((arow & 7) << 3)];
            bf16x8 bvf = *(const bf16x8*)&Bs[(bcol * 128 + colk) ^ ((bcol & 7) << 3)];
            acc = __builtin_amdgcn_mfma_f32_16x16x32_bf16(avf, bvf, acc, 0, 0, 0);
        }
    }

    // epilogue: ELU + write H_new[b][node][h*32 + col]
    #pragma unroll
    for (int q = 0; q < 4; ++q) {
        int node = row0 + wr * 16 + l4 * 4 + q;
        float v = acc[q];
        v = (v > 0.f) ? v : expm1f(v);
        outH[(size_t)(b * 2048 + node) * 128 + h * 32 + wc * 16 + l15] = v;
    }
}

extern "C" void kernel_launch(void* const* d_in, const int* in_sizes, int n_in,
                              void* d_out, int out_size, void* d_ws, size_t ws_size,
                              hipStream_t stream) {
    const float* H   = (const float*)d_in[0];
    const float* adj = (const float*)d_in[1];
    const float* W   = (const float*)d_in[2];
    const float* a   = (const float*)d_in[3];

    float* outH  = (float*)d_out;
    float* alpha = outH + (size_t)4 * 2048 * 128;   // 1048576

    char* ws = (char*)d_ws;
    __hip_bfloat16* HtT = (__hip_bfloat16*)ws;                    // 2 MB
    float* src = (float*)(ws + 2 * 1024 * 1024);                  // 128 KB
    float* dst = src + 32768;                                     // 128 KB
    unsigned char* adjI = (unsigned char*)(ws + 2 * 1024 * 1024 + 256 * 1024);  // 4 MB

    k0_adjI<<<4096, 256, 0, stream>>>(adj, adjI);
    k1_ht<<<4096, 256, 0, stream>>>(H, W, a, HtT, src, dst);
    k2_fused<<<dim3(64, 16), 256, 0, stream>>>(adjI, src, dst, HtT, alpha, outH);
}

// Round 8
// 75.560 us; speedup vs baseline: 1.2825x; 1.1711x over previous
//
#include <hip/hip_runtime.h>
#include <hip/hip_bf16.h>
#include <math.h>

// GAT: B=4, N=2048, in=128, out=32, heads=4
// outputs: H_new [4,2048,128] f32 (1048576) then alpha [4,4,2048,2048] f32 (67108864)

typedef float f32x4 __attribute__((ext_vector_type(4)));
typedef short bf16x8 __attribute__((ext_vector_type(8)));
typedef unsigned int u32;

#define LRELU 0.2f
#define LOG2E 1.44269504088896f
#define EXP2(x) __builtin_amdgcn_exp2f(x)

__device__ inline ushort f2b(float x) {
    unsigned int u = __float_as_uint(x);
    u += 0x7fffu + ((u >> 16) & 1u);   // RNE
    return (ushort)(u >> 16);
}

// ---------------- k0: adjI[row][col] = (adj!=0 || col==row) ? 1 : 0 (u8) ------------------
__global__ __launch_bounds__(256) void k0_adjI(const float* __restrict__ adj,
                                               unsigned char* __restrict__ adjI) {
    int idx = blockIdx.x * 256 + threadIdx.x;
    int e0 = idx * 4;
    int row = e0 >> 11;
    int c0 = e0 & 2047;
    float4 v = *(const float4*)(adj + (size_t)e0);
    uchar4 o;
    o.x = (v.x != 0.f || c0     == row) ? 1 : 0;
    o.y = (v.y != 0.f || c0 + 1 == row) ? 1 : 0;
    o.z = (v.z != 0.f || c0 + 2 == row) ? 1 : 0;
    o.w = (v.w != 0.f || c0 + 3 == row) ? 1 : 0;
    *(uchar4*)(adjI + (size_t)e0) = o;
}

// ---------------- k1: MFMA Ht^T = W^T @ H^T, + src/dst from accumulators ------------------
// grid (32 n-tiles of 64, 16 bh), block 256 (4 waves, each 16 n).
__global__ __launch_bounds__(256) void k1_ht(const float* __restrict__ H,
                                             const float* __restrict__ W,
                                             const float* __restrict__ a,
                                             __hip_bfloat16* __restrict__ HtT,
                                             float* __restrict__ src,
                                             float* __restrict__ dst) {
    __shared__ __align__(16) ushort Wbf[32 * 128];   // [f][i] bf16, XOR-swizzled, 8 KB

    int t = threadIdx.x;
    int ntile = blockIdx.x;   // 32
    int bh    = blockIdx.y;   // 16
    int b = bh >> 2, h = bh & 3;
    int lane = t & 63, w = t >> 6;
    int l15 = lane & 15, l4 = lane >> 4;

    // stage W[h] (128x32 f32, [i][f]) -> Wbf[f][i] bf16 swizzled
    #pragma unroll
    for (int u = 0; u < 16; ++u) {
        int idx = u * 256 + t;
        int i = idx >> 5, f = idx & 31;
        Wbf[(f * 128 + i) ^ ((f & 7) << 3)] = f2b(W[h * 4096 + idx]);
    }
    __syncthreads();

    int n = ntile * 64 + w * 16 + l15;
    const float* hrow = H + ((size_t)(b * 2048) + n) * 128;

    f32x4 acc0 = {0.f, 0.f, 0.f, 0.f};   // f rows 0-15
    f32x4 acc1 = {0.f, 0.f, 0.f, 0.f};   // f rows 16-31
    #pragma unroll
    for (int kc = 0; kc < 4; ++kc) {
        int k0 = kc * 32 + l4 * 8;
        float4 h0 = *(const float4*)(hrow + k0);
        float4 h1 = *(const float4*)(hrow + k0 + 4);
        union { u32 u[4]; bf16x8 v; } bu;
        asm("v_cvt_pk_bf16_f32 %0, %1, %2" : "=v"(bu.u[0]) : "v"(h0.x), "v"(h0.y));
        asm("v_cvt_pk_bf16_f32 %0, %1, %2" : "=v"(bu.u[1]) : "v"(h0.z), "v"(h0.w));
        asm("v_cvt_pk_bf16_f32 %0, %1, %2" : "=v"(bu.u[2]) : "v"(h1.x), "v"(h1.y));
        asm("v_cvt_pk_bf16_f32 %0, %1, %2" : "=v"(bu.u[3]) : "v"(h1.z), "v"(h1.w));
        bf16x8 bfrag = bu.v;
        bf16x8 af0 = *(const bf16x8*)&Wbf[(l15 * 128 + kc * 32 + l4 * 8) ^ ((l15 & 7) << 3)];
        bf16x8 af1 = *(const bf16x8*)&Wbf[((16 + l15) * 128 + kc * 32 + l4 * 8) ^ (((16 + l15) & 7) << 3)];
        acc0 = __builtin_amdgcn_mfma_f32_16x16x32_bf16(af0, bfrag, acc0, 0, 0, 0);
        acc1 = __builtin_amdgcn_mfma_f32_16x16x32_bf16(af1, bfrag, acc1, 0, 0, 0);
    }

    // epilogue: HtT bf16 + src/dst dots (fp32 accum)
    float sv = 0.f, dvv = 0.f;
    ushort* ht = (ushort*)HtT;
    #pragma unroll
    for (int r = 0; r < 4; ++r) {
        int f0 = l4 * 4 + r;
        sv  += acc0[r] * a[h * 64 + f0]      + acc1[r] * a[h * 64 + 16 + f0];
        dvv += acc0[r] * a[h * 64 + 32 + f0] + acc1[r] * a[h * 64 + 48 + f0];
        ht[(size_t)(bh * 32 + f0) * 2048 + n]      = f2b(acc0[r]);
        ht[(size_t)(bh * 32 + 16 + f0) * 2048 + n] = f2b(acc1[r]);
    }
    sv  += __shfl_xor(sv, 16);  sv  += __shfl_xor(sv, 32);
    dvv += __shfl_xor(dvv, 16); dvv += __shfl_xor(dvv, 32);
    if (l4 == 0) { src[bh * 2048 + n] = sv; dst[bh * 2048 + n] = dvv; }
}

// ---------------- fused: softmax -> alpha (nt-store) -> MFMA -> ELU -> H_new ---------------
// grid (64 mtiles of 32 rows, 16 bh), block 256 (4 waves).
// Pass B: loads are ALWAYS issued before stores (2 reg-set rotation + sched_barrier), so
// consuming prefetched regs never forces draining the nt-store queue (vmcnt slack ~2 chunks).
__global__ __launch_bounds__(256, 4) void k2_fused(const unsigned char* __restrict__ adjI,
                                                   const float* __restrict__ src,
                                                   const float* __restrict__ dst,
                                                   const __hip_bfloat16* __restrict__ HtT,
                                                   float* __restrict__ alpha,
                                                   float* __restrict__ outH) {
    __shared__ float dstS[2048];                      // 8 KB (pre-scaled by LOG2E)
    __shared__ float rowL[32], rowSrcS[32];
    __shared__ __align__(16) ushort As[32 * 128];     // 8 KB, XOR-swizzled alpha tile (bf16)

    int t = threadIdx.x;
    int mtile = blockIdx.x;   // 64
    int bh    = blockIdx.y;   // 16
    int lane = t & 63, w = t >> 6;
    int b = bh >> 2, h = bh & 3;
    int row0 = mtile * 32;

    const float4* dst4g = (const float4*)(dst + bh * 2048);
    #pragma unroll
    for (int u = 0; u < 2; ++u) {
        float4 v = dst4g[u * 256 + t];
        v.x *= LOG2E; v.y *= LOG2E; v.z *= LOG2E; v.w *= LOG2E;
        *(float4*)&dstS[(u * 256 + t) * 4] = v;
    }
    if (t < 32) rowSrcS[t] = src[bh * 2048 + row0 + t] * LOG2E;
    __syncthreads();

    // ---- pass A: per-row S = sum_j adjI * exp2(leaky(ee)); store L = -log2(S) ----
    for (int rr = 0; rr < 8; ++rr) {
        int r = w * 8 + rr;
        int gr = row0 + r;
        float sn = rowSrcS[r];
        const uint2* a8 = (const uint2*)(adjI + (size_t)gr * 2048);
        float S = 0.f;
        #pragma unroll
        for (int u = 0; u < 4; ++u) {
            uint2 ab = a8[u * 64 + lane];
            int jb = (u * 64 + lane) * 8;
            float4 dv0 = *(const float4*)&dstS[jb];
            float4 dv1 = *(const float4*)&dstS[jb + 4];
            float dj[8] = {dv0.x, dv0.y, dv0.z, dv0.w, dv1.x, dv1.y, dv1.z, dv1.w};
            #pragma unroll
            for (int q = 0; q < 8; ++q) {
                u32 word = (q < 4) ? ab.x : ab.y;
                float ajf = (float)((word >> (8 * (q & 3))) & 0xffu);
                float ee = sn + dj[q];
                float vm = fmaxf(ee, LRELU * ee);
                S = fmaf(EXP2(vm), ajf, S);
            }
        }
        #pragma unroll
        for (int off = 32; off; off >>= 1) S += __shfl_xor(S, off);
        if (lane == 0) rowL[r] = -__log2f(S);
    }
    __syncthreads();

    // ---- pass B ----
    f32x4 acc = {0.f, 0.f, 0.f, 0.f};
    int wr = w >> 1, wc = w & 1;
    int l15 = lane & 15, l4 = lane >> 4;
    int arow = wr * 16 + l15;
    // B-fragment source: HtT row (bh*32 + wc*16 + l15), 16B per 32-k chunk (L2-resident)
    const ushort* Bfp = (const ushort*)HtT + (size_t)(bh * 32 + wc * 16 + l15) * 2048 + l4 * 8;
    float* alphaRow = alpha + (size_t)(bh * 2048 + row0) * 2048;

    int sr = t >> 5;            // rows sr, sr+8, sr+16, sr+24
    int sc4 = t & 31;

    float snR[4], LR[4];
    #pragma unroll
    for (int u = 0; u < 4; ++u) { snR[u] = rowSrcS[sr + u * 8]; LR[u] = rowL[sr + u * 8]; }

    auto loadA = [&](int k, u32* ar) {
        #pragma unroll
        for (int u = 0; u < 4; ++u)
            ar[u] = *(const u32*)(adjI + (size_t)(row0 + sr + u * 8) * 2048 + k * 128 + sc4 * 4);
    };
    auto loadB = [&](int k, bf16x8* br) {
        #pragma unroll
        for (int kk = 0; kk < 4; ++kk)
            br[kk] = *(const bf16x8*)(Bfp + (size_t)k * 128 + kk * 32);
    };
    auto stage = [&](int k, const u32* ar) {
        int jb = k * 128 + sc4 * 4;
        float4 dv = *(const float4*)&dstS[jb];
        float dj[4] = {dv.x, dv.y, dv.z, dv.w};
        #pragma unroll
        for (int u = 0; u < 4; ++u) {
            int r = sr + u * 8;
            float sn = snR[u], L = LR[u];
            u32 ab = ar[u];
            float o[4];
            #pragma unroll
            for (int q = 0; q < 4; ++q) {
                float ajf = (float)((ab >> (8 * q)) & 0xffu);
                float ee = sn + dj[q];
                float vm = fmaxf(ee + L, fmaf(ee, LRELU, L));
                o[q] = EXP2(vm) * ajf;
            }
            f32x4 ov = {o[0], o[1], o[2], o[3]};
            __builtin_nontemporal_store(ov, (f32x4*)(alphaRow + (size_t)r * 2048 + jb));
            u32 lo, hi;
            asm("v_cvt_pk_bf16_f32 %0, %1, %2" : "=v"(lo) : "v"(o[0]), "v"(o[1]));
            asm("v_cvt_pk_bf16_f32 %0, %1, %2" : "=v"(hi) : "v"(o[2]), "v"(o[3]));
            uint2 pk = {lo, hi};
            *(uint2*)&As[(r * 128 + sc4 * 4) ^ ((r & 7) << 3)] = pk;
        }
    };
    auto mfmaPhase = [&](const bf16x8* br) {
        #pragma unroll
        for (int kk = 0; kk < 4; ++kk) {
            bf16x8 af = *(const bf16x8*)&As[(arow * 128 + kk * 32 + l4 * 8) ^ ((arow & 7) << 3)];
            acc = __builtin_amdgcn_mfma_f32_16x16x32_bf16(af, br[kk], acc, 0, 0, 0);
        }
    };

    u32 aE[4], aO[4];
    bf16x8 bE[4], bO[4];
    loadA(0, aE); loadB(0, bE);   // prologue: chunk 0 -> set E

    for (int kp = 0; kp < 8; ++kp) {
        int ke = 2 * kp, ko = 2 * kp + 1;
        // -------- even chunk (consume E; prefetch ko -> O, loads BEFORE stores) --------
        if (ke) { asm volatile("s_waitcnt lgkmcnt(0)" ::: "memory"); __builtin_amdgcn_s_barrier(); }
        loadA(ko, aO); loadB(ko, bO);
        __builtin_amdgcn_sched_barrier(0);
        stage(ke, aE);
        asm volatile("s_waitcnt lgkmcnt(0)" ::: "memory");
        __builtin_amdgcn_s_barrier();
        mfmaPhase(bE);
        // -------- odd chunk (consume O; prefetch ko+1 -> E) --------
        asm volatile("s_waitcnt lgkmcnt(0)" ::: "memory");
        __builtin_amdgcn_s_barrier();
        if (ko + 1 < 16) { loadA(ko + 1, aE); loadB(ko + 1, bE); }
        __builtin_amdgcn_sched_barrier(0);
        stage(ko, aO);
        asm volatile("s_waitcnt lgkmcnt(0)" ::: "memory");
        __builtin_amdgcn_s_barrier();
        mfmaPhase(bO);
    }

    // epilogue: ELU + write H_new[b][node][h*32 + col]
    #pragma unroll
    for (int q = 0; q < 4; ++q) {
        int node = row0 + wr * 16 + l4 * 4 + q;
        float v = acc[q];
        v = (v > 0.f) ? v : expm1f(v);
        outH[(size_t)(b * 2048 + node) * 128 + h * 32 + wc * 16 + l15] = v;
    }
}

extern "C" void kernel_launch(void* const* d_in, const int* in_sizes, int n_in,
                              void* d_out, int out_size, void* d_ws, size_t ws_size,
                              hipStream_t stream) {
    const float* H   = (const float*)d_in[0];
    const float* adj = (const float*)d_in[1];
    const float* W   = (const float*)d_in[2];
    const float* a   = (const float*)d_in[3];

    float* outH  = (float*)d_out;
    float* alpha = outH + (size_t)4 * 2048 * 128;   // 1048576

    char* ws = (char*)d_ws;
    __hip_bfloat16* HtT = (__hip_bfloat16*)ws;                    // 2 MB
    float* src = (float*)(ws + 2 * 1024 * 1024);                  // 128 KB
    float* dst = src + 32768;                                     // 128 KB
    unsigned char* adjI = (unsigned char*)(ws + 2 * 1024 * 1024 + 256 * 1024);  // 4 MB

    k0_adjI<<<4096, 256, 0, stream>>>(adj, adjI);
    k1_ht<<<dim3(32, 16), 256, 0, stream>>>(H, W, a, HtT, src, dst);
    k2_fused<<<dim3(64, 16), 256, 0, stream>>>(adjI, src, dst, HtT, alpha, outH);
}